// Round 15
// baseline (292.337 us; speedup 1.0000x reference)
//
#include <hip/hip_runtime.h>

typedef unsigned short u16;
typedef u16 u16x4 __attribute__((ext_vector_type(4)));
typedef u16 u16x8 __attribute__((ext_vector_type(8)));
typedef __bf16 bf16;
typedef bf16 bf16x8 __attribute__((ext_vector_type(8)));
typedef float f32x4 __attribute__((ext_vector_type(4)));

__device__ __forceinline__ float bf2f(u16 v) {
  union { unsigned u; float f; } x; x.u = ((unsigned)v) << 16; return x.f;
}
__device__ __forceinline__ u16 f2bf(float f) {
  union { float f; unsigned u; } x; x.f = f;
  unsigned u = x.u;
  u += 0x7fffu + ((u >> 16) & 1u);   // RNE
  return (u16)(u >> 16);
}
// hw packed f32->bf16 (RNE), 2 values / instr (no builtin on gfx950, m240)
__device__ __forceinline__ unsigned cvt2bf(float lo, float hi) {
  unsigned r;
  asm("v_cvt_pk_bf16_f32 %0, %1, %2" : "=v"(r) : "v"(lo), "v"(hi));
  return r;
}

// lgkm-only barrier: LDS drained, global loads stay in flight
__device__ __forceinline__ void bar_lgkm() {
  asm volatile("s_waitcnt lgkmcnt(0)" ::: "memory");
  __builtin_amdgcn_s_barrier();
}

// async global->LDS, 16B per lane; LDS base wave-uniform, global source per-lane (m173)
#define GLDS16(g, l) __builtin_amdgcn_global_load_lds( \
    (const __attribute__((address_space(1))) unsigned int*)(const void*)(g), \
    (__attribute__((address_space(3))) unsigned int*)(void*)(l), 16, 0, 0)

// ---------------- prep: 4 weight transposes + query cvt + small cvts (R0/R8 proven) -----
__global__ __launch_bounds__(256) void prep_k(
    const float* __restrict__ Wq, const float* __restrict__ Wk,
    const float* __restrict__ Wv, const float* __restrict__ Wout,
    const float* __restrict__ query,
    const float* __restrict__ wkds, const float* __restrict__ wvds,
    const float* __restrict__ b0, const float* __restrict__ b1,
    const float* __restrict__ b2, const float* __restrict__ b3,
    u16* __restrict__ WT, u16* __restrict__ q_bf,
    u16* __restrict__ dstW, u16* __restrict__ dstB)
{
  __shared__ u16 T[64][72];
  const int blk = blockIdx.x;
  const int t = threadIdx.x;
  if (blk < 576) {
    const int bz = blk / 144, rr = blk % 144;
    const int r0 = (rr / 12) * 64, c0 = (rr % 12) * 64;
    const float* W = (bz == 0) ? Wq : (bz == 1) ? Wk : (bz == 2) ? Wv : Wout;
    u16* O = WT + (size_t)bz * 768 * 768;
    #pragma unroll
    for (int p = 0; p < 2; ++p) {
      int v = t + p * 256;
      int r = v / 8, c = (v % 8) * 8;
      f32x4 x0 = *(const f32x4*)&W[(size_t)(r0 + r) * 768 + c0 + c];
      f32x4 x1 = *(const f32x4*)&W[(size_t)(r0 + r) * 768 + c0 + c + 4];
      #pragma unroll
      for (int i = 0; i < 4; ++i) { T[r][c + i] = f2bf(x0[i]); T[r][c + 4 + i] = f2bf(x1[i]); }
    }
    __syncthreads();
    #pragma unroll
    for (int p = 0; p < 2; ++p) {
      int v = t + p * 256;
      int r = v / 8, c = (v % 8) * 8;
      u16x8 tv;
      #pragma unroll
      for (int i = 0; i < 8; ++i) tv[i] = T[c + i][r];
      *(u16x8*)&O[(size_t)(c0 + r) * 768 + r0 + c] = tv;
    }
  } else if (blk < 6720) {
    const size_t i = (size_t)(blk - 576) * 256 + t;   // 6144*256 slots, *8 = 12582912
    f32x4 a = *(const f32x4*)&query[i * 8];
    f32x4 b = *(const f32x4*)&query[i * 8 + 4];
    u16x8 w;
    #pragma unroll
    for (int j = 0; j < 4; ++j) { w[j] = f2bf(a[j]); w[4 + j] = f2bf(b[j]); }
    *(u16x8*)&q_bf[i * 8] = w;
  } else {
    const int i = (blk - 6720) * 256 + t;   // 268*256 = 68608 = 65536 + 3072
    if (i < 32768)      dstW[i] = f2bf(wkds[i]);
    else if (i < 65536) dstW[i] = f2bf(wvds[i - 32768]);
    else {
      int j = i - 65536, s = j / 768, si = j % 768;
      const float* src = (s == 0) ? b0 : (s == 1) ? b1 : (s == 2) ? b2 : b3;
      dstB[j] = f2bf(src[si]);
    }
  }
}

// ---------------- downsample v8 (R14): coalesced GLDS + register 4x4 transpose ----------
__global__ __launch_bounds__(256) void ds_k(
    const u16* __restrict__ Wds,      // bf16 [2][64][512]
    const float* __restrict__ key, const float* __restrict__ value,
    u16* __restrict__ key_ds)         // [2][32][64][768] (key_ds ++ val_ds contiguous)
{
  __shared__ float Sg[2][64 * 64];   // 16KB each: fp32 chunk, v7 staging layout
  __shared__ u16  Kb[2][64 * 72];    // 9KB each: bf16 k-major [n][72]
  const int pair = blockIdx.y >> 5, b = blockIdx.y & 31;
  const float* src = (pair ? value : key) + (size_t)b * 512 * 768;
  const u16* W = Wds + pair * 32768;
  u16* dst = key_ds + (size_t)pair * 1572864 + (size_t)b * 49152;
  const int nt = blockIdx.x * 64;
  const int t = threadIdx.x, wave = t >> 6, lane = t & 63;
  const int wm = wave * 16;                    // 4 waves x 16 kds-rows
  const int lrow = lane & 15, quad = lane >> 4;
  const int k4 = t >> 4, n4 = t & 15;          // transpose: 4x4 block (k4*4.., n4*4..)

  bf16x8 wreg[16];
  #pragma unroll
  for (int c = 0; c < 16; ++c)
    wreg[c] = *(const bf16x8*)&W[(size_t)(wm + lrow) * 512 + c * 32 + quad * 8];

  auto stage = [&](int bufi, int kb) {
    #pragma unroll
    for (int p = 0; p < 4; ++p) {
      const int g = wave * 4 + p;
      const int row = kb + g * 4 + (lane >> 4);
      const int ch = (lane & 15) ^ (g & 15);
      GLDS16(&src[(size_t)row * 768 + nt + ch * 4], (char*)&Sg[bufi][0] + g * 1024);
    }
  };
  auto transp = [&](int bufi) {
    f32x4 r[4];
    #pragma unroll
    for (int i = 0; i < 4; ++i) {
      const int k = k4 * 4 + i;
      r[i] = *(const f32x4*)&Sg[bufi][k * 64 + ((n4 ^ (k4 & 15)) & 15) * 4];
    }
    #pragma unroll
    for (int nn = 0; nn < 4; ++nn) {
      unsigned* p2 = (unsigned*)&Kb[bufi][(n4 * 4 + nn) * 72 + k4 * 4];
      p2[0] = cvt2bf(r[0][nn], r[1][nn]);
      p2[1] = cvt2bf(r[2][nn], r[3][nn]);
    }
  };

  f32x4 acc[4] = {};
  stage(0, 0);
  __syncthreads();
  stage(1, 64);
  transp(0);
  bar_lgkm();
  int cur = 0;
  #pragma unroll
  for (int cc = 0; cc < 8; ++cc) {
    #pragma unroll
    for (int kc = 0; kc < 2; ++kc) {
      bf16x8 bv[4];
      #pragma unroll
      for (int j = 0; j < 4; ++j) {
        const int n = j * 16 + lrow;
        bv[j] = *(const bf16x8*)&Kb[cur][n * 72 + kc * 32 + quad * 8];
      }
      #pragma unroll
      for (int j = 0; j < 4; ++j)
        acc[j] = __builtin_amdgcn_mfma_f32_16x16x32_bf16(wreg[cc * 2 + kc], bv[j], acc[j], 0, 0, 0);
    }
    if (cc < 7) {
      __syncthreads();
      if (cc < 6) stage(cur, (cc + 2) * 64);
      transp(cur ^ 1);
      bar_lgkm();
      cur ^= 1;
    }
  }

  #pragma unroll
  for (int j = 0; j < 4; ++j) {
    const int col = nt + j * 16 + lrow;
    #pragma unroll
    for (int r = 0; r < 4; ++r) {
      const int row = wm + quad * 4 + r;
      dst[(size_t)row * 768 + col] = f2bf(acc[j][r]);
    }
  }
}

// ---------------- bf16 GEMM, BK=64, GLDS, swizzled, XCD-chunked (R6 proven) ----------
template<int ACT, bool OF32>
__global__ __launch_bounds__(256) void gemm64_k(
    const u16* __restrict__ A, int lda,
    const u16* __restrict__ Bt, int ldb,
    void* __restrict__ Craw, int ldc,
    const u16* __restrict__ bias, int K)
{
  __shared__ u16 As[128 * 64];   // 16KB, swizzled ch^(r&7)
  __shared__ u16 Bs[128 * 64];   // 16KB, swizzled
  const int blk = blockIdx.x;                   // 768 = 128 mt x 6 nt
  const int wg = (blk & 7) * 96 + (blk >> 3);
  const int mt = (wg / 6) * 128, nt = (wg % 6) * 128;
  const int t = threadIdx.x, wave = t >> 6, lane = t & 63;
  const int wm = (wave >> 1) * 64, wn = (wave & 1) * 64;
  const int lrow = lane & 15, quad = lane >> 4;
  f32x4 acc[4][4] = {};

  for (int k0 = 0; k0 < K; k0 += 64) {
    __syncthreads();
    #pragma unroll
    for (int p = 0; p < 4; ++p) {
      const int slot = wave * 256 + p * 64 + lane;
      const int r = slot >> 3, ch = slot & 7;
      const int chs = ch ^ (r & 7);
      const int lb = (wave * 256 + p * 64) * 8;
      GLDS16(&A[(size_t)(mt + r) * lda + k0 + chs * 8], &As[lb]);
      GLDS16(&Bt[(size_t)(nt + r) * ldb + k0 + chs * 8], &Bs[lb]);
    }
    __syncthreads();

    #pragma unroll
    for (int c = 0; c < 2; ++c) {
      bf16x8 av[4], bv[4];
      #pragma unroll
      for (int i = 0; i < 4; ++i) {
        const int row = wm + i * 16 + lrow;
        av[i] = *(const bf16x8*)&As[row * 64 + (((c * 4 + quad) ^ (row & 7)) * 8)];
      }
      #pragma unroll
      for (int j = 0; j < 4; ++j) {
        const int row = wn + j * 16 + lrow;
        bv[j] = *(const bf16x8*)&Bs[row * 64 + (((c * 4 + quad) ^ (row & 7)) * 8)];
      }
      #pragma unroll
      for (int i = 0; i < 4; ++i)
        #pragma unroll
        for (int j = 0; j < 4; ++j)
          acc[i][j] = __builtin_amdgcn_mfma_f32_16x16x32_bf16(av[i], bv[j], acc[i][j], 0, 0, 0);
    }
  }

  #pragma unroll
  for (int i = 0; i < 4; ++i) {
    #pragma unroll
    for (int j = 0; j < 4; ++j) {
      const int col = nt + wn + j * 16 + lrow;
      const float badd = bias ? bf2f(bias[col]) : 0.0f;
      #pragma unroll
      for (int r = 0; r < 4; ++r) {
        const int row = mt + wm + i * 16 + quad * 4 + r;
        float v = acc[i][j][r] + badd;
        if constexpr (ACT == 1) v = v > 0.0f ? v + 1.0f : __expf(v);
        if constexpr (OF32) ((float*)Craw)[(size_t)row * ldc + col] = v;
        else                ((u16*)Craw)[(size_t)row * ldc + col] = f2bf(v);
      }
    }
  }
}

// ---------------- fused phi_q GEMM + attention apply ----------------
// C1 = elu(q_bf @ WqT + bq)+1 (per-wave: 64 rows x ONE head's 64 cols, in regs), then
// one-shot epilogue: qz in-register (shfl_xor row-reduce), phi -> dead As/Bs LDS,
// a_v = (phi @ sT_head^T) * 1/qz written direct. Deletes attn_av launch + 75MB traffic.
__global__ __launch_bounds__(256) void gemmqa_k(
    const u16* __restrict__ A,       // q_bf [16384][768]
    const u16* __restrict__ Bt,      // WqT  [768][768]
    const u16* __restrict__ sT,      // [384][64][64]  (sT[x][h][d], k=d)
    const float* __restrict__ zbuf,  // [384][64]
    const u16* __restrict__ bias,    // bq
    u16* __restrict__ Av)            // a_v out [16384][768]
{
  __shared__ u16 As[128 * 64];   // K-loop A; epilogue: Ph head-lo
  __shared__ u16 Bs[128 * 64];   // K-loop B; epilogue: Ph head-hi
  __shared__ u16 Sv[2][64 * 72]; // sT head-lo/hi, padded (2-way banks)
  const int blk = blockIdx.x;                   // 768 = 128 mt x 6 nt
  const int wg = (blk & 7) * 96 + (blk >> 3);
  const int mt = (wg / 6) * 128, nt = (wg % 6) * 128;
  const int t = threadIdx.x, wave = t >> 6, lane = t & 63;
  const int wm = (wave >> 1) * 64, wn = (wave & 1) * 64;
  const int lrow = lane & 15, quad = lane >> 4;
  const int xb = (mt >> 9) * 12 + (nt >> 6);    // b*12 + head-lo
  f32x4 acc[4][4] = {};

  // stage sT head tiles (L2-hot, 8KB each); K-loop barriers order it before use
  #pragma unroll
  for (int p = 0; p < 2; ++p) {
    const u16* sp = sT + ((size_t)xb + p) * 4096;
    #pragma unroll
    for (int q2 = 0; q2 < 2; ++q2) {
      const int slot = t * 2 + q2;              // 512 slots
      const int r = slot >> 3, c = (slot & 7) * 8;
      *(u16x8*)&Sv[p][r * 72 + c] = *(const u16x8*)&sp[r * 64 + c];
    }
  }

  for (int k0 = 0; k0 < 768; k0 += 64) {
    __syncthreads();
    #pragma unroll
    for (int p = 0; p < 4; ++p) {
      const int slot = wave * 256 + p * 64 + lane;
      const int r = slot >> 3, ch = slot & 7;
      const int chs = ch ^ (r & 7);
      const int lb = (wave * 256 + p * 64) * 8;
      GLDS16(&A[(size_t)(mt + r) * 768 + k0 + chs * 8], &As[lb]);
      GLDS16(&Bt[(size_t)(nt + r) * 768 + k0 + chs * 8], &Bs[lb]);
    }
    __syncthreads();
    #pragma unroll
    for (int c = 0; c < 2; ++c) {
      bf16x8 av[4], bv[4];
      #pragma unroll
      for (int i = 0; i < 4; ++i) {
        const int row = wm + i * 16 + lrow;
        av[i] = *(const bf16x8*)&As[row * 64 + (((c * 4 + quad) ^ (row & 7)) * 8)];
      }
      #pragma unroll
      for (int j = 0; j < 4; ++j) {
        const int row = wn + j * 16 + lrow;
        bv[j] = *(const bf16x8*)&Bs[row * 64 + (((c * 4 + quad) ^ (row & 7)) * 8)];
      }
      #pragma unroll
      for (int i = 0; i < 4; ++i)
        #pragma unroll
        for (int j = 0; j < 4; ++j)
          acc[i][j] = __builtin_amdgcn_mfma_f32_16x16x32_bf16(av[i], bv[j], acc[i][j], 0, 0, 0);
    }
  }

  // ---- epilogue: phi = elu(acc+bias)+1 (in regs) ----
  #pragma unroll
  for (int i = 0; i < 4; ++i)
    #pragma unroll
    for (int j = 0; j < 4; ++j) {
      const float badd = bf2f(bias[nt + wn + j * 16 + lrow]);
      #pragma unroll
      for (int r = 0; r < 4; ++r) {
        float v = acc[i][j][r] + badd;
        acc[i][j][r] = v > 0.0f ? v + 1.0f : __expf(v);
      }
    }

  // qz fully in-register: per-row dot with z, reduced across the 16-lane row group
  const int x = xb + (wn >> 6);
  float zj[4];
  #pragma unroll
  for (int j = 0; j < 4; ++j) zj[j] = zbuf[(size_t)x * 64 + j * 16 + lrow];
  float qzr[4][4];   // [i][r], rows wm+i*16+quad*4+r
  #pragma unroll
  for (int i = 0; i < 4; ++i)
    #pragma unroll
    for (int r = 0; r < 4; ++r) {
      float s = 0.f;
      #pragma unroll
      for (int j = 0; j < 4; ++j) s += acc[i][j][r] * zj[j];
      s += __shfl_xor(s, 1); s += __shfl_xor(s, 2);
      s += __shfl_xor(s, 4); s += __shfl_xor(s, 8);
      qzr[i][r] = 1.0f / (s + 1e-6f);
    }

  // phi -> LDS (overlay dead As/Bs; same chunk-swizzle as K-loop)
  __syncthreads();                      // K-loop As/Bs reads complete
  u16* Ph = wn ? Bs : As;               // [128][64] per head
  #pragma unroll
  for (int i = 0; i < 4; ++i)
    #pragma unroll
    for (int j = 0; j < 4; ++j) {
      const int cj = j * 16 + lrow;
      #pragma unroll
      for (int r = 0; r < 4; ++r) {
        const int row = wm + i * 16 + quad * 4 + r;
        Ph[row * 64 + (((cj >> 3) ^ (row & 7)) * 8) + (cj & 7)] = f2bf(acc[i][j][r]);
      }
    }
  __syncthreads();                      // Ph + Sv visible

  // a_v = phi @ sT^T (k = d = 64), then scale by qzr
  const u16* Svh = Sv[wn >> 6];
  f32x4 a2[4][4] = {};
  #pragma unroll
  for (int c = 0; c < 2; ++c) {
    bf16x8 av2[4], bv2[4];
    #pragma unroll
    for (int i = 0; i < 4; ++i) {
      const int row = wm + i * 16 + lrow;
      av2[i] = *(const bf16x8*)&Ph[row * 64 + (((c * 4 + quad) ^ (row & 7)) * 8)];
    }
    #pragma unroll
    for (int j = 0; j < 4; ++j) {
      const int hr = j * 16 + lrow;
      bv2[j] = *(const bf16x8*)&Svh[hr * 72 + c * 32 + quad * 8];
    }
    #pragma unroll
    for (int i = 0; i < 4; ++i)
      #pragma unroll
      for (int j = 0; j < 4; ++j)
        a2[i][j] = __builtin_amdgcn_mfma_f32_16x16x32_bf16(av2[i], bv2[j], a2[i][j], 0, 0, 0);
  }
  #pragma unroll
  for (int i = 0; i < 4; ++i)
    #pragma unroll
    for (int j = 0; j < 4; ++j)
      #pragma unroll
      for (int r = 0; r < 4; ++r) {
        const int row = mt + wm + i * 16 + quad * 4 + r;
        Av[(size_t)row * 768 + nt + wn + j * 16 + lrow] = f2bf(a2[i][j][r] * qzr[i][r]);
      }
}

// ---------------- fused phi_k/vals GEMM + KV-state, double-buffered (R12 proven) ----------
__global__ __launch_bounds__(256) void fkv_k(
    const u16* __restrict__ key_ds,   // [2][32][64][768] bf16
    const u16* __restrict__ WT,       // WkT at +768^2, WvT at +2*768^2
    const u16* __restrict__ bias_c,   // bk at +768, bv at +1536
    u16* __restrict__ sT, float* __restrict__ z)
{
  __shared__ char sm[65536];
  u16* T0 = (u16*)sm;                 // buf b: u16 offset b*16384; tile w: +w*4096
  u16* Pt = (u16*)sm;                 // [64][72] overlay after loop
  u16* Vt = (u16*)(sm + 9216);        // [64][72]
  const int x = blockIdx.x;           // b*12 + n
  const int b = x / 12, n = x % 12;
  const int t = threadIdx.x, wave = t >> 6, lane = t & 63;
  const u16* srcs[4] = {
    key_ds + (size_t)b * 49152,
    WT + 589824 + (size_t)n * 49152,
    key_ds + 1572864 + (size_t)b * 49152,
    WT + 2 * 589824 + (size_t)n * 49152 };
  const int grow = lane >> 3;
  const int gchunk = (lane & 7) ^ (grow & 7);
  const int isV = wave & 1;
  const int wm = (wave >> 1) * 32;
  const int lrow = lane & 15, quad = lane >> 4;
  f32x4 acc[2][4] = {};

  auto stage = [&](int buf, int k0) {
    const u16* s = srcs[wave];
    char* dtile = sm + buf * 32768 + wave * 8192;
    #pragma unroll
    for (int j = 0; j < 8; ++j) {
      const u16* gsrc = s + (size_t)(j * 8 + grow) * 768 + k0 + gchunk * 8;
      GLDS16(gsrc, dtile + j * 1024);
    }
  };

  stage(0, 0);
  __syncthreads();
  int buf = 0;
  for (int ks = 0; ks < 12; ++ks) {
    if (ks < 11) stage(buf ^ 1, (ks + 1) * 64);
    const u16* Atile = T0 + buf * 16384 + (isV ? 2 : 0) * 4096;
    const u16* Btile = T0 + buf * 16384 + (isV ? 3 : 1) * 4096;
    #pragma unroll
    for (int c = 0; c < 2; ++c) {
      bf16x8 av[2], bv[4];
      #pragma unroll
      for (int i = 0; i < 2; ++i) {
        const int row = wm + i * 16 + lrow;
        av[i] = *(const bf16x8*)&Atile[row * 64 + (((c * 4 + quad) ^ (row & 7)) * 8)];
      }
      #pragma unroll
      for (int j = 0; j < 4; ++j) {
        const int row = j * 16 + lrow;
        bv[j] = *(const bf16x8*)&Btile[row * 64 + (((c * 4 + quad) ^ (row & 7)) * 8)];
      }
      #pragma unroll
      for (int i = 0; i < 2; ++i)
        #pragma unroll
        for (int j = 0; j < 4; ++j)
          acc[i][j] = __builtin_amdgcn_mfma_f32_16x16x32_bf16(av[i], bv[j], acc[i][j], 0, 0, 0);
    }
    __syncthreads();
    buf ^= 1;
  }

  const u16* bias = bias_c + (isV ? 1536 : 768) + n * 64;
  u16* Ttile = isV ? Vt : Pt;
  #pragma unroll
  for (int i = 0; i < 2; ++i)
    #pragma unroll
    for (int j = 0; j < 4; ++j) {
      const int col = j * 16 + lrow;
      const float badd = bf2f(bias[col]);
      u16x4 pk4;
      #pragma unroll
      for (int r = 0; r < 4; ++r) {
        float v = acc[i][j][r] + badd;
        if (!isV) v = v > 0.0f ? v + 1.0f : __expf(v);
        pk4[r] = f2bf(v);
      }
      *(u16x4*)&Ttile[col * 72 + wm + i * 16 + quad * 4] = pk4;
    }
  __syncthreads();

  const int wm2 = (wave >> 1) * 32, wn2 = (wave & 1) * 32;
  f32x4 a2[2][2] = {};
  #pragma unroll
  for (int c = 0; c < 2; ++c) {
    bf16x8 av[2], bv[2];
    #pragma unroll
    for (int i = 0; i < 2; ++i)
      av[i] = *(const bf16x8*)&Vt[(wm2 + i * 16 + lrow) * 72 + c * 32 + quad * 8];
    #pragma unroll
    for (int j = 0; j < 2; ++j)
      bv[j] = *(const bf16x8*)&Pt[(wn2 + j * 16 + lrow) * 72 + c * 32 + quad * 8];
    #pragma unroll
    for (int i = 0; i < 2; ++i)
      #pragma unroll
      for (int j = 0; j < 2; ++j)
        a2[i][j] = __builtin_amdgcn_mfma_f32_16x16x32_bf16(av[i], bv[j], a2[i][j], 0, 0, 0);
  }
  u16* sTg = sT + (size_t)x * 4096;
  #pragma unroll
  for (int i = 0; i < 2; ++i)
    #pragma unroll
    for (int j = 0; j < 2; ++j)
      #pragma unroll
      for (int r = 0; r < 4; ++r)
        sTg[(size_t)(wm2 + i * 16 + quad * 4 + r) * 64 + wn2 + j * 16 + lrow] = f2bf(a2[i][j][r]);
  if (t < 64) {
    float zz = 0.f;
    #pragma unroll
    for (int g = 0; g < 8; ++g) {
      u16x8 p = *(const u16x8*)&Pt[t * 72 + g * 8];
      #pragma unroll
      for (int e = 0; e < 8; ++e) zz += bf2f(p[e]);
    }
    z[(size_t)x * 64 + t] = zz;
  }
}

__global__ void tagfill_k(float* out, float val, int n) {
  int i = blockIdx.x * 256 + threadIdx.x;
  if (i < n) out[i] = val;
}

extern "C" void kernel_launch(void* const* d_in, const int* in_sizes, int n_in,
                              void* d_out, int out_size, void* d_ws, size_t ws_size,
                              hipStream_t stream) {
  (void)out_size;
  float* out = (float*)d_out;

  int o;
  if (n_in >= 14 && in_sizes[3] == 1) o = 4;
  else if (n_in == 13) o = 3;
  else { tagfill_k<<<4, 256, 0, stream>>>(out, 77.0f, 1024); return; }
  if (in_sizes[0] != 12582912 || in_sizes[o + 0] != 32768 || in_sizes[o + 2] != 589824) {
    tagfill_k<<<4, 256, 0, stream>>>(out, 88.0f, 1024); return;
  }

  const float* query = (const float*)d_in[0];
  const float* key   = (const float*)d_in[1];
  const float* value = (const float*)d_in[2];
  const float* W_kds = (const float*)d_in[o + 0];
  const float* W_vds = (const float*)d_in[o + 1];
  const float* Wq   = (const float*)d_in[o + 2];
  const float* bq   = (const float*)d_in[o + 3];
  const float* Wk   = (const float*)d_in[o + 4];
  const float* bk   = (const float*)d_in[o + 5];
  const float* Wv   = (const float*)d_in[o + 6];
  const float* bv   = (const float*)d_in[o + 7];
  const float* Wout = (const float*)d_in[o + 8];
  const float* bout = (const float*)d_in[o + 9];

  const size_t NEED = 64722944;
  if (ws_size < NEED) { tagfill_k<<<4, 256, 0, stream>>>(out, 123.0f, 1024); return; }

  char* base = (char*)d_ws;
  u16*   WT     = (u16*)base;                         // 4,718,592
  u16*   q_bf   = (u16*)(base + 4718592);             // 25,165,824 (lives thru gemmqa)
  u16*   a_v    = (u16*)(base + 29884416);            // 25,165,824
  u16*   Wds_c  = (u16*)(base + 55050240);            // 131,072
  u16*   bias_c = (u16*)(base + 55181312);            // 6,144
  u16*   key_ds = (u16*)(base + 55187456);            // 6,291,456
  u16*   sT     = (u16*)(base + 61478912);            // 3,145,728 (own region now)
  float* zbuf   = (float*)(base + 64624640);          // 98,304
  u16* WqT   = WT;
  u16* WoutT = WT + 3 * 768 * 768;
  u16* bq_c = bias_c, *bout_c = bias_c + 2304;

  // 1. prep: W transposes + query cvt + Wds/bias cvt
  prep_k<<<6988, 256, 0, stream>>>(Wq, Wk, Wv, Wout, query, W_kds, W_vds,
                                   bq, bk, bv, bout, WT, q_bf, Wds_c, bias_c);

  // 2. downsample v8
  ds_k<<<dim3(12, 64), 256, 0, stream>>>(Wds_c, key, value, key_ds);

  // 3. fused phi_k/vals + KV state
  fkv_k<<<384, 256, 0, stream>>>(key_ds, WT, bias_c, sT, zbuf);

  // 4. fused phi_q GEMM + attention apply (writes a_v directly; attn_av deleted)
  gemmqa_k<<<768, 256, 0, stream>>>(q_bf, WqT, sT, zbuf, bq_c, a_v);

  // 5. out = a_v @ Wout + bout (fp32 C, XCD-swizzled)
  gemm64_k<0, true><<<768, 256, 0, stream>>>(
      a_v, 768, WoutT, 768, out, 768, bout_c, 768);
}

// Round 16
// 287.064 us; speedup vs baseline: 1.0184x; 1.0184x over previous
//
#include <hip/hip_runtime.h>

typedef unsigned short u16;
typedef u16 u16x4 __attribute__((ext_vector_type(4)));
typedef u16 u16x8 __attribute__((ext_vector_type(8)));
typedef __bf16 bf16;
typedef bf16 bf16x8 __attribute__((ext_vector_type(8)));
typedef float f32x4 __attribute__((ext_vector_type(4)));

__device__ __forceinline__ float bf2f(u16 v) {
  union { unsigned u; float f; } x; x.u = ((unsigned)v) << 16; return x.f;
}
__device__ __forceinline__ u16 f2bf(float f) {
  union { float f; unsigned u; } x; x.f = f;
  unsigned u = x.u;
  u += 0x7fffu + ((u >> 16) & 1u);   // RNE
  return (u16)(u >> 16);
}
// hw packed f32->bf16 (RNE), 2 values / instr (no builtin on gfx950, m240)
__device__ __forceinline__ unsigned cvt2bf(float lo, float hi) {
  unsigned r;
  asm("v_cvt_pk_bf16_f32 %0, %1, %2" : "=v"(r) : "v"(lo), "v"(hi));
  return r;
}

// lgkm-only barrier: LDS drained, global loads stay in flight
__device__ __forceinline__ void bar_lgkm() {
  asm volatile("s_waitcnt lgkmcnt(0)" ::: "memory");
  __builtin_amdgcn_s_barrier();
}

// async global->LDS, 16B per lane; LDS base wave-uniform, global source per-lane (m173)
#define GLDS16(g, l) __builtin_amdgcn_global_load_lds( \
    (const __attribute__((address_space(1))) unsigned int*)(const void*)(g), \
    (__attribute__((address_space(3))) unsigned int*)(void*)(l), 16, 0, 0)

// ---------------- prep: 4 weight transposes + query cvt + small cvts (R0/R8 proven) -----
__global__ __launch_bounds__(256) void prep_k(
    const float* __restrict__ Wq, const float* __restrict__ Wk,
    const float* __restrict__ Wv, const float* __restrict__ Wout,
    const float* __restrict__ query,
    const float* __restrict__ wkds, const float* __restrict__ wvds,
    const float* __restrict__ b0, const float* __restrict__ b1,
    const float* __restrict__ b2, const float* __restrict__ b3,
    u16* __restrict__ WT, u16* __restrict__ q_bf,
    u16* __restrict__ dstW, u16* __restrict__ dstB)
{
  __shared__ u16 T[64][72];
  const int blk = blockIdx.x;
  const int t = threadIdx.x;
  if (blk < 576) {
    const int bz = blk / 144, rr = blk % 144;
    const int r0 = (rr / 12) * 64, c0 = (rr % 12) * 64;
    const float* W = (bz == 0) ? Wq : (bz == 1) ? Wk : (bz == 2) ? Wv : Wout;
    u16* O = WT + (size_t)bz * 768 * 768;
    #pragma unroll
    for (int p = 0; p < 2; ++p) {
      int v = t + p * 256;
      int r = v / 8, c = (v % 8) * 8;
      f32x4 x0 = *(const f32x4*)&W[(size_t)(r0 + r) * 768 + c0 + c];
      f32x4 x1 = *(const f32x4*)&W[(size_t)(r0 + r) * 768 + c0 + c + 4];
      #pragma unroll
      for (int i = 0; i < 4; ++i) { T[r][c + i] = f2bf(x0[i]); T[r][c + 4 + i] = f2bf(x1[i]); }
    }
    __syncthreads();
    #pragma unroll
    for (int p = 0; p < 2; ++p) {
      int v = t + p * 256;
      int r = v / 8, c = (v % 8) * 8;
      u16x8 tv;
      #pragma unroll
      for (int i = 0; i < 8; ++i) tv[i] = T[c + i][r];
      *(u16x8*)&O[(size_t)(c0 + r) * 768 + r0 + c] = tv;
    }
  } else if (blk < 6720) {
    const size_t i = (size_t)(blk - 576) * 256 + t;   // 6144*256 slots, *8 = 12582912
    f32x4 a = *(const f32x4*)&query[i * 8];
    f32x4 b = *(const f32x4*)&query[i * 8 + 4];
    u16x8 w;
    #pragma unroll
    for (int j = 0; j < 4; ++j) { w[j] = f2bf(a[j]); w[4 + j] = f2bf(b[j]); }
    *(u16x8*)&q_bf[i * 8] = w;
  } else {
    const int i = (blk - 6720) * 256 + t;   // 268*256 = 68608 = 65536 + 3072
    if (i < 32768)      dstW[i] = f2bf(wkds[i]);
    else if (i < 65536) dstW[i] = f2bf(wvds[i - 32768]);
    else {
      int j = i - 65536, s = j / 768, si = j % 768;
      const float* src = (s == 0) ? b0 : (s == 1) ? b1 : (s == 2) ? b2 : b3;
      dstB[j] = f2bf(src[si]);
    }
  }
}

// ---------------- downsample v8 (R14): coalesced GLDS + register 4x4 transpose ----------
__global__ __launch_bounds__(256) void ds_k(
    const u16* __restrict__ Wds,      // bf16 [2][64][512]
    const float* __restrict__ key, const float* __restrict__ value,
    u16* __restrict__ key_ds)         // [2][32][64][768] (key_ds ++ val_ds contiguous)
{
  __shared__ float Sg[2][64 * 64];   // 16KB each: fp32 chunk, v7 staging layout
  __shared__ u16  Kb[2][64 * 72];    // 9KB each: bf16 k-major [n][72]
  const int pair = blockIdx.y >> 5, b = blockIdx.y & 31;
  const float* src = (pair ? value : key) + (size_t)b * 512 * 768;
  const u16* W = Wds + pair * 32768;
  u16* dst = key_ds + (size_t)pair * 1572864 + (size_t)b * 49152;
  const int nt = blockIdx.x * 64;
  const int t = threadIdx.x, wave = t >> 6, lane = t & 63;
  const int wm = wave * 16;                    // 4 waves x 16 kds-rows
  const int lrow = lane & 15, quad = lane >> 4;
  const int k4 = t >> 4, n4 = t & 15;          // transpose: 4x4 block (k4*4.., n4*4..)

  bf16x8 wreg[16];
  #pragma unroll
  for (int c = 0; c < 16; ++c)
    wreg[c] = *(const bf16x8*)&W[(size_t)(wm + lrow) * 512 + c * 32 + quad * 8];

  auto stage = [&](int bufi, int kb) {
    #pragma unroll
    for (int p = 0; p < 4; ++p) {
      const int g = wave * 4 + p;
      const int row = kb + g * 4 + (lane >> 4);
      const int ch = (lane & 15) ^ (g & 15);
      GLDS16(&src[(size_t)row * 768 + nt + ch * 4], (char*)&Sg[bufi][0] + g * 1024);
    }
  };
  auto transp = [&](int bufi) {
    f32x4 r[4];
    #pragma unroll
    for (int i = 0; i < 4; ++i) {
      const int k = k4 * 4 + i;
      r[i] = *(const f32x4*)&Sg[bufi][k * 64 + ((n4 ^ (k4 & 15)) & 15) * 4];
    }
    #pragma unroll
    for (int nn = 0; nn < 4; ++nn) {
      unsigned* p2 = (unsigned*)&Kb[bufi][(n4 * 4 + nn) * 72 + k4 * 4];
      p2[0] = cvt2bf(r[0][nn], r[1][nn]);
      p2[1] = cvt2bf(r[2][nn], r[3][nn]);
    }
  };

  f32x4 acc[4] = {};
  stage(0, 0);
  __syncthreads();
  stage(1, 64);
  transp(0);
  bar_lgkm();
  int cur = 0;
  #pragma unroll
  for (int cc = 0; cc < 8; ++cc) {
    #pragma unroll
    for (int kc = 0; kc < 2; ++kc) {
      bf16x8 bv[4];
      #pragma unroll
      for (int j = 0; j < 4; ++j) {
        const int n = j * 16 + lrow;
        bv[j] = *(const bf16x8*)&Kb[cur][n * 72 + kc * 32 + quad * 8];
      }
      #pragma unroll
      for (int j = 0; j < 4; ++j)
        acc[j] = __builtin_amdgcn_mfma_f32_16x16x32_bf16(wreg[cc * 2 + kc], bv[j], acc[j], 0, 0, 0);
    }
    if (cc < 7) {
      __syncthreads();
      if (cc < 6) stage(cur, (cc + 2) * 64);
      transp(cur ^ 1);
      bar_lgkm();
      cur ^= 1;
    }
  }

  #pragma unroll
  for (int j = 0; j < 4; ++j) {
    const int col = nt + j * 16 + lrow;
    #pragma unroll
    for (int r = 0; r < 4; ++r) {
      const int row = wm + quad * 4 + r;
      dst[(size_t)row * 768 + col] = f2bf(acc[j][r]);
    }
  }
}

// ---------------- bf16 GEMM, BK=64, GLDS, swizzled, XCD-chunked (R6 proven) ----------
template<int ACT, bool OF32>
__global__ __launch_bounds__(256) void gemm64_k(
    const u16* __restrict__ A, int lda,
    const u16* __restrict__ Bt, int ldb,
    void* __restrict__ Craw, int ldc,
    const u16* __restrict__ bias, int K)
{
  __shared__ u16 As[128 * 64];   // 16KB, swizzled ch^(r&7)
  __shared__ u16 Bs[128 * 64];   // 16KB, swizzled
  const int blk = blockIdx.x;                   // 768 = 128 mt x 6 nt
  const int wg = (blk & 7) * 96 + (blk >> 3);
  const int mt = (wg / 6) * 128, nt = (wg % 6) * 128;
  const int t = threadIdx.x, wave = t >> 6, lane = t & 63;
  const int wm = (wave >> 1) * 64, wn = (wave & 1) * 64;
  const int lrow = lane & 15, quad = lane >> 4;
  f32x4 acc[4][4] = {};

  for (int k0 = 0; k0 < K; k0 += 64) {
    __syncthreads();
    #pragma unroll
    for (int p = 0; p < 4; ++p) {
      const int slot = wave * 256 + p * 64 + lane;
      const int r = slot >> 3, ch = slot & 7;
      const int chs = ch ^ (r & 7);
      const int lb = (wave * 256 + p * 64) * 8;
      GLDS16(&A[(size_t)(mt + r) * lda + k0 + chs * 8], &As[lb]);
      GLDS16(&Bt[(size_t)(nt + r) * ldb + k0 + chs * 8], &Bs[lb]);
    }
    __syncthreads();

    #pragma unroll
    for (int c = 0; c < 2; ++c) {
      bf16x8 av[4], bv[4];
      #pragma unroll
      for (int i = 0; i < 4; ++i) {
        const int row = wm + i * 16 + lrow;
        av[i] = *(const bf16x8*)&As[row * 64 + (((c * 4 + quad) ^ (row & 7)) * 8)];
      }
      #pragma unroll
      for (int j = 0; j < 4; ++j) {
        const int row = wn + j * 16 + lrow;
        bv[j] = *(const bf16x8*)&Bs[row * 64 + (((c * 4 + quad) ^ (row & 7)) * 8)];
      }
      #pragma unroll
      for (int i = 0; i < 4; ++i)
        #pragma unroll
        for (int j = 0; j < 4; ++j)
          acc[i][j] = __builtin_amdgcn_mfma_f32_16x16x32_bf16(av[i], bv[j], acc[i][j], 0, 0, 0);
    }
  }

  #pragma unroll
  for (int i = 0; i < 4; ++i) {
    #pragma unroll
    for (int j = 0; j < 4; ++j) {
      const int col = nt + wn + j * 16 + lrow;
      const float badd = bias ? bf2f(bias[col]) : 0.0f;
      #pragma unroll
      for (int r = 0; r < 4; ++r) {
        const int row = mt + wm + i * 16 + quad * 4 + r;
        float v = acc[i][j][r] + badd;
        if constexpr (ACT == 1) v = v > 0.0f ? v + 1.0f : __expf(v);
        if constexpr (OF32) ((float*)Craw)[(size_t)row * ldc + col] = v;
        else                ((u16*)Craw)[(size_t)row * ldc + col] = f2bf(v);
      }
    }
  }
}

// ---------------- fused phi_k/vals GEMM + KV-state, double-buffered (R12 proven) ----------
// R16: XCD-chunk grid swizzle — the 12 n-blocks sharing key_ds[b]/val_ds[b] now land
// on one XCD (orig = (blk&7)*48 + blk>>3; 384 = 8 x 48, bijective) -> L2 locality.
__global__ __launch_bounds__(256) void fkv_k(
    const u16* __restrict__ key_ds,   // [2][32][64][768] bf16
    const u16* __restrict__ WT,       // WkT at +768^2, WvT at +2*768^2
    const u16* __restrict__ bias_c,   // bk at +768, bv at +1536
    u16* __restrict__ sT, float* __restrict__ z)
{
  __shared__ char sm[65536];
  u16* T0 = (u16*)sm;                 // buf b: u16 offset b*16384; tile w: +w*4096
  u16* Pt = (u16*)sm;                 // [64][72] overlay after loop
  u16* Vt = (u16*)(sm + 9216);        // [64][72]
  const int x = (blockIdx.x & 7) * 48 + (blockIdx.x >> 3);   // XCD-chunked b*12+n
  const int b = x / 12, n = x % 12;
  const int t = threadIdx.x, wave = t >> 6, lane = t & 63;
  const u16* srcs[4] = {
    key_ds + (size_t)b * 49152,
    WT + 589824 + (size_t)n * 49152,
    key_ds + 1572864 + (size_t)b * 49152,
    WT + 2 * 589824 + (size_t)n * 49152 };
  const int grow = lane >> 3;
  const int gchunk = (lane & 7) ^ (grow & 7);
  const int isV = wave & 1;
  const int wm = (wave >> 1) * 32;
  const int lrow = lane & 15, quad = lane >> 4;
  f32x4 acc[2][4] = {};

  auto stage = [&](int buf, int k0) {
    const u16* s = srcs[wave];
    char* dtile = sm + buf * 32768 + wave * 8192;
    #pragma unroll
    for (int j = 0; j < 8; ++j) {
      const u16* gsrc = s + (size_t)(j * 8 + grow) * 768 + k0 + gchunk * 8;
      GLDS16(gsrc, dtile + j * 1024);
    }
  };

  stage(0, 0);
  __syncthreads();
  int buf = 0;
  for (int ks = 0; ks < 12; ++ks) {
    if (ks < 11) stage(buf ^ 1, (ks + 1) * 64);
    const u16* Atile = T0 + buf * 16384 + (isV ? 2 : 0) * 4096;
    const u16* Btile = T0 + buf * 16384 + (isV ? 3 : 1) * 4096;
    #pragma unroll
    for (int c = 0; c < 2; ++c) {
      bf16x8 av[2], bv[4];
      #pragma unroll
      for (int i = 0; i < 2; ++i) {
        const int row = wm + i * 16 + lrow;
        av[i] = *(const bf16x8*)&Atile[row * 64 + (((c * 4 + quad) ^ (row & 7)) * 8)];
      }
      #pragma unroll
      for (int j = 0; j < 4; ++j) {
        const int row = j * 16 + lrow;
        bv[j] = *(const bf16x8*)&Btile[row * 64 + (((c * 4 + quad) ^ (row & 7)) * 8)];
      }
      #pragma unroll
      for (int i = 0; i < 2; ++i)
        #pragma unroll
        for (int j = 0; j < 4; ++j)
          acc[i][j] = __builtin_amdgcn_mfma_f32_16x16x32_bf16(av[i], bv[j], acc[i][j], 0, 0, 0);
    }
    __syncthreads();
    buf ^= 1;
  }

  const u16* bias = bias_c + (isV ? 1536 : 768) + n * 64;
  u16* Ttile = isV ? Vt : Pt;
  #pragma unroll
  for (int i = 0; i < 2; ++i)
    #pragma unroll
    for (int j = 0; j < 4; ++j) {
      const int col = j * 16 + lrow;
      const float badd = bf2f(bias[col]);
      u16x4 pk4;
      #pragma unroll
      for (int r = 0; r < 4; ++r) {
        float v = acc[i][j][r] + badd;
        if (!isV) v = v > 0.0f ? v + 1.0f : __expf(v);
        pk4[r] = f2bf(v);
      }
      *(u16x4*)&Ttile[col * 72 + wm + i * 16 + quad * 4] = pk4;
    }
  __syncthreads();

  const int wm2 = (wave >> 1) * 32, wn2 = (wave & 1) * 32;
  f32x4 a2[2][2] = {};
  #pragma unroll
  for (int c = 0; c < 2; ++c) {
    bf16x8 av[2], bv[2];
    #pragma unroll
    for (int i = 0; i < 2; ++i)
      av[i] = *(const bf16x8*)&Vt[(wm2 + i * 16 + lrow) * 72 + c * 32 + quad * 8];
    #pragma unroll
    for (int j = 0; j < 2; ++j)
      bv[j] = *(const bf16x8*)&Pt[(wn2 + j * 16 + lrow) * 72 + c * 32 + quad * 8];
    #pragma unroll
    for (int i = 0; i < 2; ++i)
      #pragma unroll
      for (int j = 0; j < 2; ++j)
        a2[i][j] = __builtin_amdgcn_mfma_f32_16x16x32_bf16(av[i], bv[j], a2[i][j], 0, 0, 0);
  }
  u16* sTg = sT + (size_t)x * 4096;
  #pragma unroll
  for (int i = 0; i < 2; ++i)
    #pragma unroll
    for (int j = 0; j < 2; ++j)
      #pragma unroll
      for (int r = 0; r < 4; ++r)
        sTg[(size_t)(wm2 + i * 16 + quad * 4 + r) * 64 + wn2 + j * 16 + lrow] = f2bf(a2[i][j][r]);
  if (t < 64) {
    float zz = 0.f;
    #pragma unroll
    for (int g = 0; g < 8; ++g) {
      u16x8 p = *(const u16x8*)&Pt[t * 72 + g * 8];
      #pragma unroll
      for (int e = 0; e < 8; ++e) zz += bf2f(p[e]);
    }
    z[(size_t)x * 64 + t] = zz;
  }
}

// ---------------- a_v = (phi_q @ s) / (phi_q . z + eps), fused qz, in-place (R6) --------
__global__ __launch_bounds__(256) void attn_av_k(
    u16* __restrict__ phi_q, const u16* __restrict__ sT, const float* __restrict__ zbuf)
{
  __shared__ u16 As[64 * 72];
  __shared__ u16 Bs[64 * 72];
  __shared__ float zv[64];
  __shared__ float zpart[4][64];
  __shared__ float zq[64];
  const int x = blockIdx.x, y = blockIdx.y;
  const int b = y / 12, n = y % 12;
  const int t = threadIdx.x;
  u16* Abase = phi_q + (size_t)b * 512 * 768 + (size_t)x * 64 * 768 + n * 64;
  const u16* Bbase = sT + (size_t)y * 4096;
  if (t < 64) zv[t] = zbuf[(size_t)y * 64 + t];
  #pragma unroll
  for (int p = 0; p < 2; ++p) {
    int v = t + p * 256;
    int r = v >> 3, c = (v & 7) * 8;
    *(u16x8*)&As[r * 72 + c] = *(const u16x8*)&Abase[(size_t)r * 768 + c];
    *(u16x8*)&Bs[r * 72 + c] = *(const u16x8*)&Bbase[r * 64 + c];
  }
  __syncthreads();
  {
    int r = t & 63, seg = t >> 6;
    float s = 0.f;
    #pragma unroll
    for (int j = 0; j < 16; ++j) s += bf2f(As[r * 72 + seg * 16 + j]) * zv[seg * 16 + j];
    zpart[seg][r] = s;
  }
  __syncthreads();
  if (t < 64) {
    float s = zpart[0][t] + zpart[1][t] + zpart[2][t] + zpart[3][t];
    zq[t] = 1.0f / (s + 1e-6f);
  }
  const int wave = t >> 6, lane = t & 63;
  const int wm = (wave >> 1) * 32, wn = (wave & 1) * 32;
  const int lrow = lane & 15, quad = lane >> 4;
  f32x4 acc[2][2] = {};
  #pragma unroll
  for (int c = 0; c < 2; ++c) {
    bf16x8 av[2], bv[2];
    #pragma unroll
    for (int i = 0; i < 2; ++i) av[i] = *(const bf16x8*)&As[(wm + i * 16 + lrow) * 72 + c * 32 + quad * 8];
    #pragma unroll
    for (int j = 0; j < 2; ++j) bv[j] = *(const bf16x8*)&Bs[(wn + j * 16 + lrow) * 72 + c * 32 + quad * 8];
    #pragma unroll
    for (int i = 0; i < 2; ++i)
      #pragma unroll
      for (int j = 0; j < 2; ++j)
        acc[i][j] = __builtin_amdgcn_mfma_f32_16x16x32_bf16(av[i], bv[j], acc[i][j], 0, 0, 0);
  }
  __syncthreads();
  #pragma unroll
  for (int i = 0; i < 2; ++i)
    #pragma unroll
    for (int j = 0; j < 2; ++j) {
      const int col = wn + j * 16 + lrow;
      #pragma unroll
      for (int r = 0; r < 4; ++r) {
        const int row = wm + i * 16 + quad * 4 + r;
        Abase[(size_t)row * 768 + col] = f2bf(acc[i][j][r] * zq[row]);
      }
    }
}

__global__ void tagfill_k(float* out, float val, int n) {
  int i = blockIdx.x * 256 + threadIdx.x;
  if (i < n) out[i] = val;
}

extern "C" void kernel_launch(void* const* d_in, const int* in_sizes, int n_in,
                              void* d_out, int out_size, void* d_ws, size_t ws_size,
                              hipStream_t stream) {
  (void)out_size;
  float* out = (float*)d_out;

  int o;
  if (n_in >= 14 && in_sizes[3] == 1) o = 4;
  else if (n_in == 13) o = 3;
  else { tagfill_k<<<4, 256, 0, stream>>>(out, 77.0f, 1024); return; }
  if (in_sizes[0] != 12582912 || in_sizes[o + 0] != 32768 || in_sizes[o + 2] != 589824) {
    tagfill_k<<<4, 256, 0, stream>>>(out, 88.0f, 1024); return;
  }

  const float* query = (const float*)d_in[0];
  const float* key   = (const float*)d_in[1];
  const float* value = (const float*)d_in[2];
  const float* W_kds = (const float*)d_in[o + 0];
  const float* W_vds = (const float*)d_in[o + 1];
  const float* Wq   = (const float*)d_in[o + 2];
  const float* bq   = (const float*)d_in[o + 3];
  const float* Wk   = (const float*)d_in[o + 4];
  const float* bk   = (const float*)d_in[o + 5];
  const float* Wv   = (const float*)d_in[o + 6];
  const float* bv   = (const float*)d_in[o + 7];
  const float* Wout = (const float*)d_in[o + 8];
  const float* bout = (const float*)d_in[o + 9];

  const size_t NEED = 61478912;
  if (ws_size < NEED) { tagfill_k<<<4, 256, 0, stream>>>(out, 123.0f, 1024); return; }

  char* base = (char*)d_ws;
  u16*   WT     = (u16*)base;                         // 4,718,592
  char*  Breg   = base + 4718592;                     // 25,165,824 region
  u16*   q_bf   = (u16*)Breg;                         // dies after phi_q GEMM
  u16*   sT     = (u16*)Breg;                         // then sT (over dead q_bf)
  float* zbuf   = (float*)(Breg + 3145728);
  u16*   phi_q  = (u16*)(base + 29884416);            // 25,165,824
  u16*   Wds_c  = (u16*)(base + 55050240);            // 131,072
  u16*   bias_c = (u16*)(base + 55181312);            // 6,144
  u16*   key_ds = (u16*)(base + 55187456);            // 6,291,456
  u16* a_v = phi_q;
  u16* WqT   = WT;
  u16* WoutT = WT + 3 * 768 * 768;
  u16* bq_c = bias_c, *bout_c = bias_c + 2304;

  // 1. prep: W transposes + query cvt + Wds/bias cvt
  prep_k<<<6988, 256, 0, stream>>>(Wq, Wk, Wv, Wout, query, W_kds, W_vds,
                                   bq, bk, bv, bout, WT, q_bf, Wds_c, bias_c);

  // 2. phi_q = elu(q_bf @ WqT + bq) + 1  (bf16 A, GLDS, BK=64)
  gemm64_k<1, false><<<768, 256, 0, stream>>>(
      q_bf, 768, WqT, 768, phi_q, 768, bq_c, 768);

  // 3. downsample v8 (coalesced GLDS + register transpose + k-major LDS)
  ds_k<<<dim3(12, 64), 256, 0, stream>>>(Wds_c, key, value, key_ds);

  // 4. fused phi_k/vals + KV state, dbuf + XCD-chunked (sT/zbuf overwrite dead q_bf)
  fkv_k<<<384, 256, 0, stream>>>(key_ds, WT, bias_c, sT, zbuf);

  // 5. a_v = (phi_q @ s) * 1/(phi_q.z+eps), fused qz, in-place
  attn_av_k<<<dim3(8, 384), 256, 0, stream>>>(phi_q, sT, zbuf);

  // 6. out = a_v @ Wout + bout (fp32 C, XCD-swizzled)
  gemm64_k<0, true><<<768, 256, 0, stream>>>(
      a_v, 768, WoutT, 768, out, 768, bout_c, 768);
}

// Round 17
// 282.447 us; speedup vs baseline: 1.0350x; 1.0163x over previous
//
#include <hip/hip_runtime.h>

typedef unsigned short u16;
typedef u16 u16x4 __attribute__((ext_vector_type(4)));
typedef u16 u16x8 __attribute__((ext_vector_type(8)));
typedef __bf16 bf16;
typedef bf16 bf16x8 __attribute__((ext_vector_type(8)));
typedef float f32x4 __attribute__((ext_vector_type(4)));

__device__ __forceinline__ float bf2f(u16 v) {
  union { unsigned u; float f; } x; x.u = ((unsigned)v) << 16; return x.f;
}
__device__ __forceinline__ u16 f2bf(float f) {
  union { float f; unsigned u; } x; x.f = f;
  unsigned u = x.u;
  u += 0x7fffu + ((u >> 16) & 1u);   // RNE
  return (u16)(u >> 16);
}
// hw packed f32->bf16 (RNE), 2 values / instr (no builtin on gfx950, m240)
__device__ __forceinline__ unsigned cvt2bf(float lo, float hi) {
  unsigned r;
  asm("v_cvt_pk_bf16_f32 %0, %1, %2" : "=v"(r) : "v"(lo), "v"(hi));
  return r;
}

// lgkm-only barrier: LDS drained, global loads stay in flight
__device__ __forceinline__ void bar_lgkm() {
  asm volatile("s_waitcnt lgkmcnt(0)" ::: "memory");
  __builtin_amdgcn_s_barrier();
}

// async global->LDS, 16B per lane; LDS base wave-uniform, global source per-lane (m173)
#define GLDS16(g, l) __builtin_amdgcn_global_load_lds( \
    (const __attribute__((address_space(1))) unsigned int*)(const void*)(g), \
    (__attribute__((address_space(3))) unsigned int*)(void*)(l), 16, 0, 0)

// ---------------- prep: 4 weight transposes + query cvt + bias cvts ----------------
// grid 6732: [0,576) transpose4; [576,6720) query fp32->bf16; [6720,6732) bias (3072)
// (Wds cvt removed: ds now reads W_kds/W_vds fp32 direct)
__global__ __launch_bounds__(256) void prep_k(
    const float* __restrict__ Wq, const float* __restrict__ Wk,
    const float* __restrict__ Wv, const float* __restrict__ Wout,
    const float* __restrict__ query,
    const float* __restrict__ b0, const float* __restrict__ b1,
    const float* __restrict__ b2, const float* __restrict__ b3,
    u16* __restrict__ WT, u16* __restrict__ q_bf, u16* __restrict__ dstB)
{
  __shared__ u16 T[64][72];
  const int blk = blockIdx.x;
  const int t = threadIdx.x;
  if (blk < 576) {
    const int bz = blk / 144, rr = blk % 144;
    const int r0 = (rr / 12) * 64, c0 = (rr % 12) * 64;
    const float* W = (bz == 0) ? Wq : (bz == 1) ? Wk : (bz == 2) ? Wv : Wout;
    u16* O = WT + (size_t)bz * 768 * 768;
    #pragma unroll
    for (int p = 0; p < 2; ++p) {
      int v = t + p * 256;
      int r = v / 8, c = (v % 8) * 8;
      f32x4 x0 = *(const f32x4*)&W[(size_t)(r0 + r) * 768 + c0 + c];
      f32x4 x1 = *(const f32x4*)&W[(size_t)(r0 + r) * 768 + c0 + c + 4];
      #pragma unroll
      for (int i = 0; i < 4; ++i) { T[r][c + i] = f2bf(x0[i]); T[r][c + 4 + i] = f2bf(x1[i]); }
    }
    __syncthreads();
    #pragma unroll
    for (int p = 0; p < 2; ++p) {
      int v = t + p * 256;
      int r = v / 8, c = (v % 8) * 8;
      u16x8 tv;
      #pragma unroll
      for (int i = 0; i < 8; ++i) tv[i] = T[c + i][r];
      *(u16x8*)&O[(size_t)(c0 + r) * 768 + r0 + c] = tv;
    }
  } else if (blk < 6720) {
    const size_t i = (size_t)(blk - 576) * 256 + t;   // 6144*256 slots, *8 = 12582912
    f32x4 a = *(const f32x4*)&query[i * 8];
    f32x4 b = *(const f32x4*)&query[i * 8 + 4];
    u16x8 w;
    #pragma unroll
    for (int j = 0; j < 4; ++j) { w[j] = f2bf(a[j]); w[4 + j] = f2bf(b[j]); }
    *(u16x8*)&q_bf[i * 8] = w;
  } else {
    const int i = (blk - 6720) * 256 + t;   // 3072
    if (i < 3072) {
      int s = i / 768, si = i % 768;
      const float* src = (s == 0) ? b0 : (s == 1) ? b1 : (s == 2) ? b2 : b3;
      dstB[i] = f2bf(src[si]);
    }
  }
}

// ---------------- merged phi_q GEMM + downsample (parity-interleaved roles) ----------------
// Even blk: gemm64 phi_q = elu(q_bf@WqT+bq)+1 (R6-proven, compute-bound, ~1 TB/s).
// Odd blk:  ds v8 (R14-proven, BW-floor-bound ~2.1 TB/s, MFMA 2%).
// Independent once ds reads W fp32 direct (R10 ldW). Union LDS = 50KB costs gemm ZERO
// occupancy (its 768-grid was 3/CU anyway); ds's idle CU cycles absorb gemm's MFMA.
__global__ __launch_bounds__(256) void gds_k(
    const u16* __restrict__ A,        // q_bf
    const u16* __restrict__ Bt,       // WqT
    u16* __restrict__ C,              // phi_q
    const u16* __restrict__ bias,     // bq
    const float* __restrict__ W_kds, const float* __restrict__ W_vds,
    const float* __restrict__ key, const float* __restrict__ value,
    u16* __restrict__ key_ds)
{
  __shared__ char sm[51200];
  const int t = threadIdx.x, wave = t >> 6, lane = t & 63;
  const int lrow = lane & 15, quad = lane >> 4;
  const int sub = blockIdx.x >> 1;

  if ((blockIdx.x & 1) == 0) {
    // ---- gemm64 branch (sub in [0,768)) ----
    u16* As = (u16*)sm;               // 16KB, swizzled ch^(r&7)
    u16* Bs = (u16*)(sm + 16384);     // 16KB
    const int wg = (sub & 7) * 96 + (sub >> 3);
    const int mt = (wg / 6) * 128, nt = (wg % 6) * 128;
    const int wm = (wave >> 1) * 64, wn = (wave & 1) * 64;
    f32x4 acc[4][4] = {};

    for (int k0 = 0; k0 < 768; k0 += 64) {
      __syncthreads();
      #pragma unroll
      for (int p = 0; p < 4; ++p) {
        const int slot = wave * 256 + p * 64 + lane;
        const int r = slot >> 3, ch = slot & 7;
        const int chs = ch ^ (r & 7);
        const int lb = (wave * 256 + p * 64) * 8;
        GLDS16(&A[(size_t)(mt + r) * 768 + k0 + chs * 8], &As[lb]);
        GLDS16(&Bt[(size_t)(nt + r) * 768 + k0 + chs * 8], &Bs[lb]);
      }
      __syncthreads();
      #pragma unroll
      for (int c = 0; c < 2; ++c) {
        bf16x8 av[4], bv[4];
        #pragma unroll
        for (int i = 0; i < 4; ++i) {
          const int row = wm + i * 16 + lrow;
          av[i] = *(const bf16x8*)&As[row * 64 + (((c * 4 + quad) ^ (row & 7)) * 8)];
        }
        #pragma unroll
        for (int j = 0; j < 4; ++j) {
          const int row = wn + j * 16 + lrow;
          bv[j] = *(const bf16x8*)&Bs[row * 64 + (((c * 4 + quad) ^ (row & 7)) * 8)];
        }
        #pragma unroll
        for (int i = 0; i < 4; ++i)
          #pragma unroll
          for (int j = 0; j < 4; ++j)
            acc[i][j] = __builtin_amdgcn_mfma_f32_16x16x32_bf16(av[i], bv[j], acc[i][j], 0, 0, 0);
      }
    }
    #pragma unroll
    for (int i = 0; i < 4; ++i)
      #pragma unroll
      for (int j = 0; j < 4; ++j) {
        const int col = nt + wn + j * 16 + lrow;
        const float badd = bf2f(bias[col]);
        #pragma unroll
        for (int r = 0; r < 4; ++r) {
          const int row = mt + wm + i * 16 + quad * 4 + r;
          float v = acc[i][j][r] + badd;
          v = v > 0.0f ? v + 1.0f : __expf(v);
          C[(size_t)row * 768 + col] = f2bf(v);
        }
      }
    return;
  }

  // ---- ds v8 branch (sub in [0,768)): coalesced GLDS + register 4x4 transpose ----
  const int id = sub;
  const int nt = (id % 12) * 64;
  const int yb = id / 12;
  const int pair = yb >> 5, b = yb & 31;
  const float* src = (pair ? value : key) + (size_t)b * 512 * 768;
  const float* W32 = pair ? W_vds : W_kds;     // fp32 [64][512], L2-hot
  u16* dst = key_ds + (size_t)pair * 1572864 + (size_t)b * 49152;
  const int wm = wave * 16;
  const int k4 = t >> 4, n4 = t & 15;

  // W preload fp32-direct (R10 ldW numerics: cvt2bf RNE)
  bf16x8 wreg[16];
  #pragma unroll
  for (int c = 0; c < 16; ++c) {
    const float* wr = &W32[(size_t)(wm + lrow) * 512 + c * 32 + quad * 8];
    f32x4 w0 = *(const f32x4*)wr;
    f32x4 w1 = *(const f32x4*)(wr + 4);
    union { unsigned u[4]; bf16x8 v; } cv;
    cv.u[0] = cvt2bf(w0[0], w0[1]); cv.u[1] = cvt2bf(w0[2], w0[3]);
    cv.u[2] = cvt2bf(w1[0], w1[1]); cv.u[3] = cvt2bf(w1[2], w1[3]);
    wreg[c] = cv.v;
  }

  auto Sg = [&](int bufi) -> float* { return (float*)(sm + bufi * 16384); };
  auto Kb = [&](int bufi) -> u16*   { return (u16*)(sm + 32768 + bufi * 9216); };

  auto stage = [&](int bufi, int kb) {
    #pragma unroll
    for (int p = 0; p < 4; ++p) {
      const int g = wave * 4 + p;
      const int row = kb + g * 4 + (lane >> 4);
      const int ch = (lane & 15) ^ (g & 15);
      GLDS16(&src[(size_t)row * 768 + nt + ch * 4], (char*)Sg(bufi) + g * 1024);
    }
  };
  auto transp = [&](int bufi) {
    float* S = Sg(bufi);
    u16* K = Kb(bufi);
    f32x4 r[4];
    #pragma unroll
    for (int i = 0; i < 4; ++i) {
      const int k = k4 * 4 + i;
      r[i] = *(const f32x4*)&S[k * 64 + ((n4 ^ (k4 & 15)) & 15) * 4];
    }
    #pragma unroll
    for (int nn = 0; nn < 4; ++nn) {
      unsigned* p2 = (unsigned*)&K[(n4 * 4 + nn) * 72 + k4 * 4];
      p2[0] = cvt2bf(r[0][nn], r[1][nn]);
      p2[1] = cvt2bf(r[2][nn], r[3][nn]);
    }
  };

  f32x4 acc[4] = {};
  stage(0, 0);
  __syncthreads();
  stage(1, 64);
  transp(0);
  bar_lgkm();
  int cur = 0;
  #pragma unroll
  for (int cc = 0; cc < 8; ++cc) {
    #pragma unroll
    for (int kc = 0; kc < 2; ++kc) {
      bf16x8 bv[4];
      #pragma unroll
      for (int j = 0; j < 4; ++j) {
        const int n = j * 16 + lrow;
        bv[j] = *(const bf16x8*)&Kb(cur)[n * 72 + kc * 32 + quad * 8];
      }
      #pragma unroll
      for (int j = 0; j < 4; ++j)
        acc[j] = __builtin_amdgcn_mfma_f32_16x16x32_bf16(wreg[cc * 2 + kc], bv[j], acc[j], 0, 0, 0);
    }
    if (cc < 7) {
      __syncthreads();
      if (cc < 6) stage(cur, (cc + 2) * 64);
      transp(cur ^ 1);
      bar_lgkm();
      cur ^= 1;
    }
  }

  #pragma unroll
  for (int j = 0; j < 4; ++j) {
    const int col = nt + j * 16 + lrow;
    #pragma unroll
    for (int r = 0; r < 4; ++r) {
      const int row = wm + quad * 4 + r;
      dst[(size_t)row * 768 + col] = f2bf(acc[j][r]);
    }
  }
}

// ---------------- bf16 GEMM, BK=64, GLDS, swizzled, XCD-chunked (R6 proven) ----------
template<int ACT, bool OF32>
__global__ __launch_bounds__(256) void gemm64_k(
    const u16* __restrict__ A, int lda,
    const u16* __restrict__ Bt, int ldb,
    void* __restrict__ Craw, int ldc,
    const u16* __restrict__ bias, int K)
{
  __shared__ u16 As[128 * 64];   // 16KB, swizzled ch^(r&7)
  __shared__ u16 Bs[128 * 64];   // 16KB, swizzled
  const int blk = blockIdx.x;                   // 768 = 128 mt x 6 nt
  const int wg = (blk & 7) * 96 + (blk >> 3);
  const int mt = (wg / 6) * 128, nt = (wg % 6) * 128;
  const int t = threadIdx.x, wave = t >> 6, lane = t & 63;
  const int wm = (wave >> 1) * 64, wn = (wave & 1) * 64;
  const int lrow = lane & 15, quad = lane >> 4;
  f32x4 acc[4][4] = {};

  for (int k0 = 0; k0 < K; k0 += 64) {
    __syncthreads();
    #pragma unroll
    for (int p = 0; p < 4; ++p) {
      const int slot = wave * 256 + p * 64 + lane;
      const int r = slot >> 3, ch = slot & 7;
      const int chs = ch ^ (r & 7);
      const int lb = (wave * 256 + p * 64) * 8;
      GLDS16(&A[(size_t)(mt + r) * lda + k0 + chs * 8], &As[lb]);
      GLDS16(&Bt[(size_t)(nt + r) * ldb + k0 + chs * 8], &Bs[lb]);
    }
    __syncthreads();

    #pragma unroll
    for (int c = 0; c < 2; ++c) {
      bf16x8 av[4], bv[4];
      #pragma unroll
      for (int i = 0; i < 4; ++i) {
        const int row = wm + i * 16 + lrow;
        av[i] = *(const bf16x8*)&As[row * 64 + (((c * 4 + quad) ^ (row & 7)) * 8)];
      }
      #pragma unroll
      for (int j = 0; j < 4; ++j) {
        const int row = wn + j * 16 + lrow;
        bv[j] = *(const bf16x8*)&Bs[row * 64 + (((c * 4 + quad) ^ (row & 7)) * 8)];
      }
      #pragma unroll
      for (int i = 0; i < 4; ++i)
        #pragma unroll
        for (int j = 0; j < 4; ++j)
          acc[i][j] = __builtin_amdgcn_mfma_f32_16x16x32_bf16(av[i], bv[j], acc[i][j], 0, 0, 0);
    }
  }

  #pragma unroll
  for (int i = 0; i < 4; ++i) {
    #pragma unroll
    for (int j = 0; j < 4; ++j) {
      const int col = nt + wn + j * 16 + lrow;
      const float badd = bias ? bf2f(bias[col]) : 0.0f;
      #pragma unroll
      for (int r = 0; r < 4; ++r) {
        const int row = mt + wm + i * 16 + quad * 4 + r;
        float v = acc[i][j][r] + badd;
        if constexpr (ACT == 1) v = v > 0.0f ? v + 1.0f : __expf(v);
        if constexpr (OF32) ((float*)Craw)[(size_t)row * ldc + col] = v;
        else                ((u16*)Craw)[(size_t)row * ldc + col] = f2bf(v);
      }
    }
  }
}

// ---------------- fused phi_k/vals GEMM + KV-state, dbuf + XCD-chunked (R16 proven) -----
__global__ __launch_bounds__(256) void fkv_k(
    const u16* __restrict__ key_ds,   // [2][32][64][768] bf16
    const u16* __restrict__ WT,       // WkT at +768^2, WvT at +2*768^2
    const u16* __restrict__ bias_c,   // bk at +768, bv at +1536
    u16* __restrict__ sT, float* __restrict__ z)
{
  __shared__ char sm[65536];
  u16* T0 = (u16*)sm;
  u16* Pt = (u16*)sm;                 // [64][72] overlay after loop
  u16* Vt = (u16*)(sm + 9216);        // [64][72]
  const int x = (blockIdx.x & 7) * 48 + (blockIdx.x >> 3);   // XCD-chunked b*12+n
  const int b = x / 12, n = x % 12;
  const int t = threadIdx.x, wave = t >> 6, lane = t & 63;
  const u16* srcs[4] = {
    key_ds + (size_t)b * 49152,
    WT + 589824 + (size_t)n * 49152,
    key_ds + 1572864 + (size_t)b * 49152,
    WT + 2 * 589824 + (size_t)n * 49152 };
  const int grow = lane >> 3;
  const int gchunk = (lane & 7) ^ (grow & 7);
  const int isV = wave & 1;
  const int wm = (wave >> 1) * 32;
  const int lrow = lane & 15, quad = lane >> 4;
  f32x4 acc[2][4] = {};

  auto stage = [&](int buf, int k0) {
    const u16* s = srcs[wave];
    char* dtile = sm + buf * 32768 + wave * 8192;
    #pragma unroll
    for (int j = 0; j < 8; ++j) {
      const u16* gsrc = s + (size_t)(j * 8 + grow) * 768 + k0 + gchunk * 8;
      GLDS16(gsrc, dtile + j * 1024);
    }
  };

  stage(0, 0);
  __syncthreads();
  int buf = 0;
  for (int ks = 0; ks < 12; ++ks) {
    if (ks < 11) stage(buf ^ 1, (ks + 1) * 64);
    const u16* Atile = T0 + buf * 16384 + (isV ? 2 : 0) * 4096;
    const u16* Btile = T0 + buf * 16384 + (isV ? 3 : 1) * 4096;
    #pragma unroll
    for (int c = 0; c < 2; ++c) {
      bf16x8 av[2], bv[4];
      #pragma unroll
      for (int i = 0; i < 2; ++i) {
        const int row = wm + i * 16 + lrow;
        av[i] = *(const bf16x8*)&Atile[row * 64 + (((c * 4 + quad) ^ (row & 7)) * 8)];
      }
      #pragma unroll
      for (int j = 0; j < 4; ++j) {
        const int row = j * 16 + lrow;
        bv[j] = *(const bf16x8*)&Btile[row * 64 + (((c * 4 + quad) ^ (row & 7)) * 8)];
      }
      #pragma unroll
      for (int i = 0; i < 2; ++i)
        #pragma unroll
        for (int j = 0; j < 4; ++j)
          acc[i][j] = __builtin_amdgcn_mfma_f32_16x16x32_bf16(av[i], bv[j], acc[i][j], 0, 0, 0);
    }
    __syncthreads();
    buf ^= 1;
  }

  const u16* bias = bias_c + (isV ? 1536 : 768) + n * 64;
  u16* Ttile = isV ? Vt : Pt;
  #pragma unroll
  for (int i = 0; i < 2; ++i)
    #pragma unroll
    for (int j = 0; j < 4; ++j) {
      const int col = j * 16 + lrow;
      const float badd = bf2f(bias[col]);
      u16x4 pk4;
      #pragma unroll
      for (int r = 0; r < 4; ++r) {
        float v = acc[i][j][r] + badd;
        if (!isV) v = v > 0.0f ? v + 1.0f : __expf(v);
        pk4[r] = f2bf(v);
      }
      *(u16x4*)&Ttile[col * 72 + wm + i * 16 + quad * 4] = pk4;
    }
  __syncthreads();

  const int wm2 = (wave >> 1) * 32, wn2 = (wave & 1) * 32;
  f32x4 a2[2][2] = {};
  #pragma unroll
  for (int c = 0; c < 2; ++c) {
    bf16x8 av[2], bv[2];
    #pragma unroll
    for (int i = 0; i < 2; ++i)
      av[i] = *(const bf16x8*)&Vt[(wm2 + i * 16 + lrow) * 72 + c * 32 + quad * 8];
    #pragma unroll
    for (int j = 0; j < 2; ++j)
      bv[j] = *(const bf16x8*)&Pt[(wn2 + j * 16 + lrow) * 72 + c * 32 + quad * 8];
    #pragma unroll
    for (int i = 0; i < 2; ++i)
      #pragma unroll
      for (int j = 0; j < 2; ++j)
        a2[i][j] = __builtin_amdgcn_mfma_f32_16x16x32_bf16(av[i], bv[j], a2[i][j], 0, 0, 0);
  }
  u16* sTg = sT + (size_t)x * 4096;
  #pragma unroll
  for (int i = 0; i < 2; ++i)
    #pragma unroll
    for (int j = 0; j < 2; ++j)
      #pragma unroll
      for (int r = 0; r < 4; ++r)
        sTg[(size_t)(wm2 + i * 16 + quad * 4 + r) * 64 + wn2 + j * 16 + lrow] = f2bf(a2[i][j][r]);
  if (t < 64) {
    float zz = 0.f;
    #pragma unroll
    for (int g = 0; g < 8; ++g) {
      u16x8 p = *(const u16x8*)&Pt[t * 72 + g * 8];
      #pragma unroll
      for (int e = 0; e < 8; ++e) zz += bf2f(p[e]);
    }
    z[(size_t)x * 64 + t] = zz;
  }
}

// ---------------- a_v = (phi_q @ s) / (phi_q . z + eps), fused qz, in-place (R6) --------
__global__ __launch_bounds__(256) void attn_av_k(
    u16* __restrict__ phi_q, const u16* __restrict__ sT, const float* __restrict__ zbuf)
{
  __shared__ u16 As[64 * 72];
  __shared__ u16 Bs[64 * 72];
  __shared__ float zv[64];
  __shared__ float zpart[4][64];
  __shared__ float zq[64];
  const int x = blockIdx.x, y = blockIdx.y;
  const int b = y / 12, n = y % 12;
  const int t = threadIdx.x;
  u16* Abase = phi_q + (size_t)b * 512 * 768 + (size_t)x * 64 * 768 + n * 64;
  const u16* Bbase = sT + (size_t)y * 4096;
  if (t < 64) zv[t] = zbuf[(size_t)y * 64 + t];
  #pragma unroll
  for (int p = 0; p < 2; ++p) {
    int v = t + p * 256;
    int r = v >> 3, c = (v & 7) * 8;
    *(u16x8*)&As[r * 72 + c] = *(const u16x8*)&Abase[(size_t)r * 768 + c];
    *(u16x8*)&Bs[r * 72 + c] = *(const u16x8*)&Bbase[r * 64 + c];
  }
  __syncthreads();
  {
    int r = t & 63, seg = t >> 6;
    float s = 0.f;
    #pragma unroll
    for (int j = 0; j < 16; ++j) s += bf2f(As[r * 72 + seg * 16 + j]) * zv[seg * 16 + j];
    zpart[seg][r] = s;
  }
  __syncthreads();
  if (t < 64) {
    float s = zpart[0][t] + zpart[1][t] + zpart[2][t] + zpart[3][t];
    zq[t] = 1.0f / (s + 1e-6f);
  }
  const int wave = t >> 6, lane = t & 63;
  const int wm = (wave >> 1) * 32, wn = (wave & 1) * 32;
  const int lrow = lane & 15, quad = lane >> 4;
  f32x4 acc[2][2] = {};
  #pragma unroll
  for (int c = 0; c < 2; ++c) {
    bf16x8 av[2], bv[2];
    #pragma unroll
    for (int i = 0; i < 2; ++i) av[i] = *(const bf16x8*)&As[(wm + i * 16 + lrow) * 72 + c * 32 + quad * 8];
    #pragma unroll
    for (int j = 0; j < 2; ++j) bv[j] = *(const bf16x8*)&Bs[(wn + j * 16 + lrow) * 72 + c * 32 + quad * 8];
    #pragma unroll
    for (int i = 0; i < 2; ++i)
      #pragma unroll
      for (int j = 0; j < 2; ++j)
        acc[i][j] = __builtin_amdgcn_mfma_f32_16x16x32_bf16(av[i], bv[j], acc[i][j], 0, 0, 0);
  }
  __syncthreads();
  #pragma unroll
  for (int i = 0; i < 2; ++i)
    #pragma unroll
    for (int j = 0; j < 2; ++j) {
      const int col = wn + j * 16 + lrow;
      #pragma unroll
      for (int r = 0; r < 4; ++r) {
        const int row = wm + i * 16 + quad * 4 + r;
        Abase[(size_t)row * 768 + col] = f2bf(acc[i][j][r] * zq[row]);
      }
    }
}

__global__ void tagfill_k(float* out, float val, int n) {
  int i = blockIdx.x * 256 + threadIdx.x;
  if (i < n) out[i] = val;
}

extern "C" void kernel_launch(void* const* d_in, const int* in_sizes, int n_in,
                              void* d_out, int out_size, void* d_ws, size_t ws_size,
                              hipStream_t stream) {
  (void)out_size;
  float* out = (float*)d_out;

  int o;
  if (n_in >= 14 && in_sizes[3] == 1) o = 4;
  else if (n_in == 13) o = 3;
  else { tagfill_k<<<4, 256, 0, stream>>>(out, 77.0f, 1024); return; }
  if (in_sizes[0] != 12582912 || in_sizes[o + 0] != 32768 || in_sizes[o + 2] != 589824) {
    tagfill_k<<<4, 256, 0, stream>>>(out, 88.0f, 1024); return;
  }

  const float* query = (const float*)d_in[0];
  const float* key   = (const float*)d_in[1];
  const float* value = (const float*)d_in[2];
  const float* W_kds = (const float*)d_in[o + 0];
  const float* W_vds = (const float*)d_in[o + 1];
  const float* Wq   = (const float*)d_in[o + 2];
  const float* bq   = (const float*)d_in[o + 3];
  const float* Wk   = (const float*)d_in[o + 4];
  const float* bk   = (const float*)d_in[o + 5];
  const float* Wv   = (const float*)d_in[o + 6];
  const float* bv   = (const float*)d_in[o + 7];
  const float* Wout = (const float*)d_in[o + 8];
  const float* bout = (const float*)d_in[o + 9];

  const size_t NEED = 61478912;
  if (ws_size < NEED) { tagfill_k<<<4, 256, 0, stream>>>(out, 123.0f, 1024); return; }

  char* base = (char*)d_ws;
  u16*   WT     = (u16*)base;                         // 4,718,592
  char*  Breg   = base + 4718592;                     // 25,165,824 region
  u16*   q_bf   = (u16*)Breg;                         // dies after gds (phi_q GEMM)
  u16*   sT     = (u16*)Breg;                         // then sT (over dead q_bf)
  float* zbuf   = (float*)(Breg + 3145728);
  u16*   phi_q  = (u16*)(base + 29884416);            // 25,165,824
  u16*   bias_c = (u16*)(base + 55181312);            // 6,144
  u16*   key_ds = (u16*)(base + 55187456);            // 6,291,456
  u16* a_v = phi_q;
  u16* WqT   = WT;
  u16* WoutT = WT + 3 * 768 * 768;
  u16* bq_c = bias_c, *bout_c = bias_c + 2304;

  // 1. prep: W transposes + query cvt + bias cvt
  prep_k<<<6732, 256, 0, stream>>>(Wq, Wk, Wv, Wout, query,
                                   bq, bk, bv, bout, WT, q_bf, bias_c);

  // 2. merged phi_q GEMM + downsample (parity-interleaved; ds reads W fp32 direct)
  gds_k<<<1536, 256, 0, stream>>>(q_bf, WqT, phi_q, bq_c,
                                  W_kds, W_vds, key, value, key_ds);

  // 3. fused phi_k/vals + KV state, dbuf + XCD-chunked (sT/zbuf overwrite dead q_bf)
  fkv_k<<<384, 256, 0, stream>>>(key_ds, WT, bias_c, sT, zbuf);

  // 4. a_v = (phi_q @ s) * 1/(phi_q.z+eps), fused qz, in-place
  attn_av_k<<<dim3(8, 384), 256, 0, stream>>>(phi_q, sT, zbuf);

  // 5. out = a_v @ Wout + bout (fp32 C, XCD-swizzled)
  gemm64_k<0, true><<<768, 256, 0, stream>>>(
      a_v, 768, WoutT, 768, out, 768, bout_c, 768);
}